// Round 18
// baseline (1839.168 us; speedup 1.0000x reference)
//
#include <hip/hip_runtime.h>
#include <hip/hip_bf16.h>
#include <stdint.h>

typedef __attribute__((ext_vector_type(8))) short short8v;  // MFMA bf16 A/B frag
typedef __attribute__((ext_vector_type(4))) float float4v;  // MFMA C/D frag

#define DEVI __device__ __forceinline__

constexpr int BATCH = 256;
constexpr int NN   = 81;
constexpr int HID  = 96;
constexpr int NOUT = 9;
constexpr int BLOCK = 512;   // 8 waves = 2/SIMD; proven 124-VGPR no-spill config
constexpr int LDA = 100;   // f32 LDS row stride (floats)
constexpr int LDB = 104;   // bf16 LDS row stride (shorts): 208B, 16B-aligned

// LDS float offsets.
constexpr int OFF_XG = 0;        // f32 81x96   Xg (iteration-invariant)
constexpr int OFF_H0 = 7776;     // bf16 h buffer A
constexpr int OFF_H1 = 11988;    // bf16 h buffer B
constexpr int OFF_MS = 16200;    // f32 81x100 Msum (atomics)  / B2 bf16 scratch
constexpr int OFF_AP = 24300;    // f32 81x100 self-proj       / B1 bf16 scratch
constexpr int OFF_BV = 32400;    // f32 81x100 neighbor-proj
constexpr int SMEM_F = 40500;    // 162,000 B <= 163,840

// packed weights in d_ws (shorts): hi tiles [(ct*3+kt)*512 + lane*8 + j], lo at +ntiles*512.
constexpr int W_REL0A = 0;       // rel_w0 rows 0..95   (18 tiles)
constexpr int W_REL0B = 18432;   // rel_w0 rows 96..191 (18)
constexpr int W_REL1  = 36864;   // (18)
constexpr int W_COMB  = 55296;   // rel_w2 @ g_w0[96:192]  96x96 (18)
constexpr int W_G1    = 73728;   // (18)
constexpr int W_IHC   = 92160;   // g_w2 @ wih  96x384 (72)
constexpr int W_HH    = 165888;  // (72)
constexpr int W_R0    = 239616;  // (18)
constexpr int W_R1    = 258048;  // (18)
constexpr int W_R2    = 276480;  // 96x16, cols 9..15 zero (3)
constexpr int W_IN1   = 279552;  // (18)
constexpr int W_IN2   = 297984;  // (18)
constexpr int W_G0A   = 316416;  // g_w0 rows 0..95 (18) -> ends 334848
constexpr int BC2OFF  = 334848;  // f32[384]: g_b2 @ wih   (768 shorts)
constexpr int B3OFF   = 335616;  // f32[96]:  20*rel_b2 @ g_w0[96:]  (192 shorts)
constexpr int HISTOFF = 335808;  // bf16 hist[it][b][81*96], written iff DEFER

DEVI float sigm(float x)  { return 1.f / (1.f + __expf(-x)); }
DEVI float tanh_(float x) { return 1.f - 2.f / (__expf(2.f * x) + 1.f); }

DEVI short bfhi(float x) { union { float f; unsigned u; } v; v.f = x; return (short)(v.u >> 16); }
DEVI float fromBits(short s) { union { unsigned u; float f; } v; v.u = ((unsigned)(unsigned short)s) << 16; return v.f; }
DEVI short bfrne(float x) {
  union { float f; unsigned u; } v; v.f = x;
  unsigned r = v.u + 0x7fffu + ((v.u >> 16) & 1u);
  return (short)(r >> 16);
}
DEVI void split1(float x, short& h, short& l) { h = bfhi(x); l = bfrne(x - fromBits(h)); }

// f32 LDS row -> RNE bf16 fragment (for f32-resident inputs: MS, prologue AP)
DEVI void packFrag(const float* p, short8v& v) {
  const float4 a = *reinterpret_cast<const float4*>(p);
  const float4 b = *reinterpret_cast<const float4*>(p + 4);
  v[0] = bfrne(a.x); v[1] = bfrne(a.y); v[2] = bfrne(a.z); v[3] = bfrne(a.w);
  v[4] = bfrne(b.x); v[5] = bfrne(b.y); v[6] = bfrne(b.z); v[7] = bfrne(b.w);
}
// t0 = relu(Ap_row + Bv_row), RNE-packed (f32 inputs)
DEVI void packFragPair(const float* ap, const float* bp, short8v& v) {
  const float4 a0 = *reinterpret_cast<const float4*>(ap);
  const float4 a1 = *reinterpret_cast<const float4*>(ap + 4);
  const float4 b0 = *reinterpret_cast<const float4*>(bp);
  const float4 b1 = *reinterpret_cast<const float4*>(bp + 4);
  v[0] = bfrne(fmaxf(a0.x + b0.x, 0.f)); v[1] = bfrne(fmaxf(a0.y + b0.y, 0.f));
  v[2] = bfrne(fmaxf(a0.z + b0.z, 0.f)); v[3] = bfrne(fmaxf(a0.w + b0.w, 0.f));
  v[4] = bfrne(fmaxf(a1.x + b1.x, 0.f)); v[5] = bfrne(fmaxf(a1.y + b1.y, 0.f));
  v[6] = bfrne(fmaxf(a1.z + b1.z, 0.f)); v[7] = bfrne(fmaxf(a1.w + b1.w, 0.f));
}

// acc += A * (Wh + Wl): 2 MFMAs
DEVI float4v mfma2(short8v a, short8v bh, short8v bl, float4v acc) {
  acc = __builtin_amdgcn_mfma_f32_16x16x32_bf16(a, bh, acc, 0, 0, 0);
  acc = __builtin_amdgcn_mfma_f32_16x16x32_bf16(a, bl, acc, 0, 0, 0);
  return acc;
}

// e-th Sudoku peer of node n (order-free: message sum is permutation-invariant)
DEVI int nbr_of(int n, int e) {
  const int r = n / 9, c = n - 9 * r;
  if (e < 8)  { int cc = c + 1 + e;  if (cc >= 9) cc -= 9; return r * 9 + cc; }
  if (e < 16) { int rr = r + e - 7;  if (rr >= 9) rr -= 9; return rr * 9 + c; }
  const int q = e - 16, dr = 1 + (q >> 1), dc = 1 + (q & 1);
  const int rm = r % 3, cm = c % 3;
  int rr = r - rm + rm + dr; rr -= (rm + dr >= 3) ? 3 : 0;
  int cc = c - cm + cm + dc; cc -= (cm + dc >= 3) ? 3 : 0;
  return rr * 9 + cc;
}

// ---------------- weight pack kernel (r17-identical) ----------------
__global__ __launch_bounds__(64)
void pack_kernel(const float* rel_w0, const float* rel_w1, const float* rel_w2,
                 const float* g_w0, const float* g_w1, const float* g_w2,
                 const float* wih, const float* whh,
                 const float* r_w0, const float* r_w1, const float* r_w2,
                 const float* in_w1, const float* in_w2,
                 const float* rel_b2, const float* g_b2, short* ws)
{
  const int lane = threadIdx.x;
  const int blk = blockIdx.x;
  if (blk == 327) {  // fused biases
    float* bc2 = reinterpret_cast<float*>(ws + BC2OFF);
    float* b3  = reinterpret_cast<float*>(ws + B3OFF);
    for (int c = lane; c < 384; c += 64) {
      float a = 0.f;
      for (int t = 0; t < 96; ++t) a += g_b2[t] * wih[t * 384 + c];
      bc2[c] = a;
    }
    for (int c = lane; c < 96; c += 64) {
      float a = 0.f;
      for (int t = 0; t < 96; ++t) a += 20.f * rel_b2[t] * g_w0[(96 + t) * 96 + c];
      b3[c] = a;
    }
    return;
  }
  const int starts[14] = {0,18,36,54,72,90,162,234,252,270,273,291,309,327};
  int mi = 0;
  while (blk >= starts[mi + 1]) ++mi;
  const int tt = blk - starts[mi];
  const int ntile = starts[mi + 1] - starts[mi];
  const int kt = tt % 3, ct = tt / 3;
  const int q = lane >> 4, r = lane & 15;
  int off, C = 96, row0 = 0;
  const float* src = nullptr;
  switch (mi) {
    case 0:  src = rel_w0; off = W_REL0A; break;
    case 1:  src = rel_w0; row0 = 96; off = W_REL0B; break;
    case 2:  src = rel_w1; off = W_REL1; break;
    case 3:  off = W_COMB; break;                      // computed product
    case 4:  src = g_w1; off = W_G1; break;
    case 5:  C = 384; off = W_IHC; break;              // computed product
    case 6:  src = whh; C = 384; off = W_HH; break;
    case 7:  src = r_w0; off = W_R0; break;
    case 8:  src = r_w1; off = W_R1; break;
    case 9:  src = r_w2; C = 9; off = W_R2; break;
    case 10: src = in_w1; off = W_IN1; break;
    case 11: src = in_w2; off = W_IN2; break;
    default: src = g_w0; off = W_G0A; break;
  }
  const int c = ct * 16 + r;
  short* hd = ws + off + tt * 512 + lane * 8;
  short* ld = hd + ntile * 512;
  if (mi == 3 || mi == 5) {   // W[k][c] = sum_t A[k][t] * B[t][c] in f32, then split
    const float* A  = (mi == 3) ? rel_w2 : g_w2;            // 96 x 96
    const float* Bm = (mi == 3) ? (g_w0 + 96 * 96) : wih;   // 96 x C2
    const int C2 = (mi == 3) ? 96 : 384;
    float acc[8] = {0,0,0,0,0,0,0,0};
    for (int t = 0; t < 96; ++t) {
      const float bv = Bm[t * C2 + c];
      #pragma unroll
      for (int j = 0; j < 8; ++j) acc[j] += A[(kt * 32 + q * 8 + j) * 96 + t] * bv;
    }
    #pragma unroll
    for (int j = 0; j < 8; ++j) { short h, l; split1(acc[j], h, l); hd[j] = h; ld[j] = l; }
  } else {
    #pragma unroll
    for (int j = 0; j < 8; ++j) {
      const int k = row0 + kt * 32 + q * 8 + j;
      float w = (c < C) ? src[k * C + c] : 0.f;
      short h, l; split1(w, h, l);
      hd[j] = h; ld[j] = l;
    }
  }
}

// -------- node-GEMM stage (r10-proven): 18 tasks (3 rtp x 6 ct), 2 row-subs --------
template<bool ABF, bool OBF, bool RELU, bool XGADD>
DEVI void stage96(float* sm, int aOff, const short* WS, int wOff, int wTiles,
                  const float* bias, float bscale, int dOff, int dstLDf,
                  int wave, int lane)
{
  const int rl = lane & 15, q = lane >> 4;
  const int plane = wTiles * 512;
  const short* asb = reinterpret_cast<const short*>(sm + aOff);
  short* dsb = reinterpret_cast<short*>(sm + dOff);
  float* dsf = sm + dOff;
  #pragma unroll 1
  for (int t = wave; t < 18; t += 8) {
    const int rtp = t % 3, ct = t / 3;
    short8v a2[2][3];
    #pragma unroll
    for (int sub = 0; sub < 2; ++sub) {
      const int row = rtp * 32 + sub * 16 + rl;
      if (ABF) {
        const short* ap = asb + row * LDB + q * 8;
        #pragma unroll
        for (int kt = 0; kt < 3; ++kt)
          a2[sub][kt] = *reinterpret_cast<const short8v*>(ap + kt * 32);
      } else {
        const float* ap = &sm[aOff + row * LDA + q * 8];
        #pragma unroll
        for (int kt = 0; kt < 3; ++kt) packFrag(ap + kt * 32, a2[sub][kt]);
      }
    }
    float4v acc0 = {0.f, 0.f, 0.f, 0.f}, acc1 = {0.f, 0.f, 0.f, 0.f};
    #pragma unroll
    for (int kt = 0; kt < 3; ++kt) {
      const short* bp = WS + wOff + (ct * 3 + kt) * 512 + lane * 8;
      const short8v bh = *reinterpret_cast<const short8v*>(bp);
      const short8v bl = *reinterpret_cast<const short8v*>(bp + plane);
      acc0 = mfma2(a2[0][kt], bh, bl, acc0);
      acc1 = mfma2(a2[1][kt], bh, bl, acc1);
    }
    const int col = ct * 16 + rl;
    #pragma unroll
    for (int sub = 0; sub < 2; ++sub) {
      #pragma unroll
      for (int j = 0; j < 4; ++j) {
        const int row = rtp * 32 + sub * 16 + q * 4 + j;
        if (row < NN) {
          float v = sub ? acc1[j] : acc0[j];
          if (bias)  v += bias[col] * bscale;
          if (XGADD) v += sm[OFF_XG + row * 96 + col];
          if (RELU)  v = fmaxf(v, 0.f);
          if (OBF) dsb[row * LDB + col] = bfrne(v);
          else     dsf[row * dstLDf + col] = v;
        }
      }
    }
  }
}

// ---------------- main kernel ----------------
template<bool DEFER>
__global__ __launch_bounds__(BLOCK) __attribute__((amdgpu_waves_per_eu(1, 2)))
void rrn_kernel(const int* __restrict__ grids, const int* __restrict__ itersp,
                const float* __restrict__ emb, const float* __restrict__ in_w0,
                const float* __restrict__ in_b0, const float* __restrict__ in_b1,
                const float* __restrict__ in_b2,
                const float* __restrict__ rel_b0, const float* __restrict__ rel_b1,
                const float* __restrict__ g_b0, const float* __restrict__ g_b1,
                const float* __restrict__ bih, const float* __restrict__ bhh,
                const float* __restrict__ r_b0, const float* __restrict__ r_b1,
                const float* __restrict__ r_b2,
                const float* __restrict__ c0, const short* __restrict__ WS,
                short* __restrict__ hist, float* __restrict__ out)
{
  __shared__ float sm[SMEM_F];
  const int b = blockIdx.x, tid = threadIdx.x;
  const int wave = tid >> 6, lane = tid & 63;
  const int rl = lane & 15, q = lane >> 4;
  const int iters = itersp[0];

  // LSTM cell state, 8-wave task mapping: task t = wave + ti*8 (t<36): cc=t/6, rt=t%6.
  // Max 5 tasks/wave (waves 0-3), 4 (waves 4-7) -> all 8 waves busy in phase 7.
  float creg[5][4];
  #pragma unroll
  for (int ti = 0; ti < 5; ++ti)
    #pragma unroll
    for (int j = 0; j < 4; ++j) creg[ti][j] = 0.f;
  #pragma unroll
  for (int ti = 0; ti < 5; ++ti) {
    const int t = wave + ti * 8;
    if (t < 36) {
      const int cc = t / 6, rt = t % 6;
      #pragma unroll
      for (int j = 0; j < 4; ++j) {
        const int n = rt * 16 + q * 4 + j, col = cc * 16 + rl;
        creg[ti][j] = (n < NN) ? c0[(size_t)b * NN * HID + n * HID + col] : 0.f;
      }
    }
  }

  // ---- prologue: embed L0 (VALU, K=16) -> AP f32, then MFMA stages ----
  for (int t = tid; t < NN * HID; t += BLOCK) {
    const int n = t / HID, col = t - n * HID;
    const int g = grids[b * NN + n];
    float acc = in_b0[col];
    #pragma unroll
    for (int k = 0; k < 16; ++k) acc += emb[g * 16 + k] * in_w0[k * HID + col];
    sm[OFF_AP + n * LDA + col] = fmaxf(acc, 0.f);
  }
  __syncthreads();
  stage96<false, true, true,  false>(sm, OFF_AP, WS, W_IN1, 18, in_b1, 1.f, OFF_MS, 0, wave, lane);
  __syncthreads();
  stage96<true,  true, false, false>(sm, OFF_MS, WS, W_IN2, 18, in_b2, 1.f, OFF_H0, 0, wave, lane);
  __syncthreads();
  stage96<true, false, false, false>(sm, OFF_H0, WS, W_G0A, 18, g_b0,  1.f, OFF_XG, 96, wave, lane);
  __syncthreads();

  const float* b3ptr = reinterpret_cast<const float*>(WS + B3OFF);
  const float* bc2   = reinterpret_cast<const float*>(WS + BC2OFF);

  for (int it = 0; it < iters; ++it) {
    const int hc = (it & 1) ? OFF_H1 : OFF_H0;   // current h (bf16)
    const int hn = (it & 1) ? OFF_H0 : OFF_H1;   // next h (bf16)

    // phase 1: zero Msum; Ap = h@rel_w0[0:96] + rel_b0 (f32); Bv = h@rel_w0[96:192] (f32)
    for (int i = tid; i < 8100; i += BLOCK) sm[OFF_MS + i] = 0.f;
    stage96<true, false, false, false>(sm, hc, WS, W_REL0A, 18, rel_b0, 1.f, OFF_AP, LDA, wave, lane);
    stage96<true, false, false, false>(sm, hc, WS, W_REL0B, 18, nullptr, 0.f, OFF_BV, LDA, wave, lane);
    __syncthreads();

    // phase 2: pair GEMM, 51 wave-private groups of 32 pair-rows; LDS atomics
    #pragma unroll 1
    for (int g2 = wave; g2 < 51; g2 += 8) {
      short8v a2[2][3];
      #pragma unroll
      for (int sub = 0; sub < 2; ++sub) {
        const int row = g2 * 32 + sub * 16 + rl;
        if (row < 1620) {
          const int n = row / 20, e = row - 20 * n, m = nbr_of(n, e);
          const float* ap = &sm[OFF_AP + n * LDA + q * 8];
          const float* bp = &sm[OFF_BV + m * LDA + q * 8];
          #pragma unroll
          for (int kt = 0; kt < 3; ++kt)
            packFragPair(ap + kt * 32, bp + kt * 32, a2[sub][kt]);
        } else {
          const short8v z = {0,0,0,0,0,0,0,0};
          #pragma unroll
          for (int kt = 0; kt < 3; ++kt) a2[sub][kt] = z;
        }
      }
      #pragma unroll 1
      for (int ct = 0; ct < 6; ++ct) {
        const float rb1c = rel_b1[ct * 16 + rl];
        float4v acc0 = {0,0,0,0}, acc1 = {0,0,0,0};
        #pragma unroll
        for (int kt = 0; kt < 3; ++kt) {
          const short* bp = WS + W_REL1 + (ct * 3 + kt) * 512 + lane * 8;
          const short8v bh = *reinterpret_cast<const short8v*>(bp);
          const short8v bl = *reinterpret_cast<const short8v*>(bp + 18 * 512);
          acc0 = mfma2(a2[0][kt], bh, bl, acc0);
          acc1 = mfma2(a2[1][kt], bh, bl, acc1);
        }
        const int col = ct * 16 + rl;
        #pragma unroll
        for (int sub = 0; sub < 2; ++sub) {
          const int r0 = g2 * 32 + sub * 16 + q * 4;  // 4 rows, same node (20%4==0)
          if (r0 < 1620) {
            const int node = r0 / 20;
            const float4v a = sub ? acc1 : acc0;
            const float s = fmaxf(a[0] + rb1c, 0.f) + fmaxf(a[1] + rb1c, 0.f)
                          + fmaxf(a[2] + rb1c, 0.f) + fmaxf(a[3] + rb1c, 0.f);
            atomicAdd(&sm[OFF_MS + node * LDA + col], s);
          }
        }
        __builtin_amdgcn_sched_barrier(0);
      }
    }
    __syncthreads();

    // ph3' (fused): g0 = relu(Xg + Msum@W_COMB + b3) -> B1 bf16 (AP region)
    stage96<false, true, true, true>(sm, OFF_MS, WS, W_COMB, 18, b3ptr, 1.f, OFF_AP, 0, wave, lane);
    __syncthreads();
    // ph5: g1 = relu(g0@g_w1 + g_b1) -> B2 bf16 (MS region)
    stage96<true, true, true, false>(sm, OFF_AP, WS, W_G1, 18, g_b1, 1.f, OFF_MS, 0, wave, lane);
    __syncthreads();

    // phase 7 (8-wave balanced): per task (cc,rt): gates = g1@W_IHC + h@whh + biases
    {
      const short* xs = reinterpret_cast<const short*>(sm + OFF_MS);  // g1
      const short* hs = reinterpret_cast<const short*>(sm + hc);
      short* hnp = reinterpret_cast<short*>(sm + hn);
      short* hg = hist + (size_t)(it * BATCH + b) * (NN * HID);
      #pragma unroll
      for (int ti = 0; ti < 5; ++ti) {
        const int t = wave + ti * 8;
        if (t < 36) {
          const int cc = t / 6, rt = t % 6;
          const int colh = cc * 16 + rl;
          const float bI = bih[colh]       + bhh[colh]       + bc2[colh];
          const float bF = bih[96 + colh]  + bhh[96 + colh]  + bc2[96 + colh];
          const float bG = bih[192 + colh] + bhh[192 + colh] + bc2[192 + colh];
          const float bO = bih[288 + colh] + bhh[288 + colh] + bc2[288 + colh];
          const int row = rt * 16 + rl;
          short8v af[6];
          #pragma unroll
          for (int kt = 0; kt < 3; ++kt)
            af[kt] = *reinterpret_cast<const short8v*>(xs + row * LDB + kt * 32 + q * 8);
          #pragma unroll
          for (int kt = 3; kt < 6; ++kt)
            af[kt] = *reinterpret_cast<const short8v*>(hs + row * LDB + (kt - 3) * 32 + q * 8);
          float4v ga[4];
          #pragma unroll
          for (int gate = 0; gate < 4; ++gate) {
            const int ct = gate * 6 + cc;
            float4v acc = {0.f, 0.f, 0.f, 0.f};
            #pragma unroll
            for (int kt = 0; kt < 3; ++kt) {
              const short* bp = WS + W_IHC + (ct * 3 + kt) * 512 + lane * 8;
              acc = mfma2(af[kt], *reinterpret_cast<const short8v*>(bp),
                          *reinterpret_cast<const short8v*>(bp + 72 * 512), acc);
            }
            __builtin_amdgcn_sched_barrier(0);
            #pragma unroll
            for (int kt = 3; kt < 6; ++kt) {
              const short* bp = WS + W_HH + (ct * 3 + kt - 3) * 512 + lane * 8;
              acc = mfma2(af[kt], *reinterpret_cast<const short8v*>(bp),
                          *reinterpret_cast<const short8v*>(bp + 72 * 512), acc);
            }
            ga[gate] = acc;
            __builtin_amdgcn_sched_barrier(0);
          }
          #pragma unroll
          for (int j = 0; j < 4; ++j) {
            const int n = rt * 16 + q * 4 + j;
            const float gi = ga[0][j] + bI;
            const float gf = ga[1][j] + bF;
            const float gg = ga[2][j] + bG;
            const float go = ga[3][j] + bO;
            const float c2 = sigm(gf) * creg[ti][j] + sigm(gi) * tanh_(gg);
            creg[ti][j] = c2;
            if (n < NN) {
              const short hb = bfrne(sigm(go) * tanh_(c2));
              hnp[n * LDB + colh] = hb;
              if (DEFER) hg[n * HID + colh] = hb;
            }
          }
        }
      }
    }
    __syncthreads();

    if constexpr (!DEFER) {
      stage96<true, true, true, false>(sm, hn, WS, W_R0, 18, r_b0, 1.f, OFF_AP, 0, wave, lane);
      __syncthreads();
      stage96<true, true, true, false>(sm, OFF_AP, WS, W_R1, 18, r_b1, 1.f, OFF_MS, 0, wave, lane);
      __syncthreads();
      if (wave < 6) {
        const int rt6 = wave;
        const short* asb = reinterpret_cast<const short*>(sm + OFF_MS);
        const int row = rt6 * 16 + rl;
        short8v a2[3];
        #pragma unroll
        for (int kt = 0; kt < 3; ++kt)
          a2[kt] = *reinterpret_cast<const short8v*>(asb + row * LDB + kt * 32 + q * 8);
        float4v acc = {0,0,0,0};
        #pragma unroll
        for (int kt = 0; kt < 3; ++kt) {
          const short* bp = WS + W_R2 + kt * 512 + lane * 8;
          acc = mfma2(a2[kt], *reinterpret_cast<const short8v*>(bp),
                      *reinterpret_cast<const short8v*>(bp + 3 * 512), acc);
        }
        if (rl < NOUT) {
          float* op = out + ((size_t)it * BATCH + b) * NN * NOUT;
          #pragma unroll
          for (int j = 0; j < 4; ++j) {
            const int r2 = rt6 * 16 + q * 4 + j;
            if (r2 < NN) op[r2 * NOUT + rl] = acc[j] + r_b2[rl];
          }
        }
      }
      __syncthreads();
    }
  }
}

// ---------------- deferred readout kernel: grid (BATCH, iters), 53.7KB LDS -> 3 blk/CU ----------------
constexpr int RO_H  = 0;
constexpr int RO_B1 = 4212;
constexpr int RO_B2 = 8424;
constexpr int RO_F  = 13416;  // + pad so row-95 fragment reads stay in-bounds

__global__ __launch_bounds__(BLOCK)
void readout_kernel(const short* __restrict__ hist, const short* __restrict__ WS,
                    const float* __restrict__ r_b0, const float* __restrict__ r_b1,
                    const float* __restrict__ r_b2, float* __restrict__ out)
{
  __shared__ float sm[RO_F];
  const int b = blockIdx.x, it = blockIdx.y;
  const int tid = threadIdx.x, wave = tid >> 6, lane = tid & 63;
  const int rl = lane & 15, q = lane >> 4;

  short* hx = reinterpret_cast<short*>(sm + RO_H);
  const short* src = hist + (size_t)(it * BATCH + b) * (NN * HID);
  for (int t = tid; t < NN * HID; t += BLOCK) {
    const int n = t / HID, c = t - n * HID;
    hx[n * LDB + c] = src[t];
  }
  __syncthreads();
  stage96<true, true, true, false>(sm, RO_H,  WS, W_R0, 18, r_b0, 1.f, RO_B1, 0, wave, lane);
  __syncthreads();
  stage96<true, true, true, false>(sm, RO_B1, WS, W_R1, 18, r_b1, 1.f, RO_B2, 0, wave, lane);
  __syncthreads();
  if (wave < 6) {
    const int rt6 = wave;
    const short* asb = reinterpret_cast<const short*>(sm + RO_B2);
    const int row = rt6 * 16 + rl;
    short8v a2[3];
    #pragma unroll
    for (int kt = 0; kt < 3; ++kt)
      a2[kt] = *reinterpret_cast<const short8v*>(asb + row * LDB + kt * 32 + q * 8);
    float4v acc = {0,0,0,0};
    #pragma unroll
    for (int kt = 0; kt < 3; ++kt) {
      const short* bp = WS + W_R2 + kt * 512 + lane * 8;
      acc = mfma2(a2[kt], *reinterpret_cast<const short8v*>(bp),
                  *reinterpret_cast<const short8v*>(bp + 3 * 512), acc);
    }
    if (rl < NOUT) {
      float* op = out + ((size_t)it * BATCH + b) * NN * NOUT;
      #pragma unroll
      for (int j = 0; j < 4; ++j) {
        const int r2 = rt6 * 16 + q * 4 + j;
        if (r2 < NN) op[r2 * NOUT + rl] = acc[j] + r_b2[rl];
      }
    }
  }
}

extern "C" void kernel_launch(void* const* d_in, const int* in_sizes, int n_in,
                              void* d_out, int out_size, void* d_ws, size_t ws_size,
                              hipStream_t stream) {
  (void)in_sizes; (void)n_in;
  const int* grids = (const int*)d_in[0];
  const int* iters = (const int*)d_in[1];
  const float *emb = (const float*)d_in[2],
    *in_w0 = (const float*)d_in[3],  *in_b0 = (const float*)d_in[4],
    *in_w1 = (const float*)d_in[5],  *in_b1 = (const float*)d_in[6],
    *in_w2 = (const float*)d_in[7],  *in_b2 = (const float*)d_in[8],
    *rel_w0 = (const float*)d_in[9],  *rel_b0 = (const float*)d_in[10],
    *rel_w1 = (const float*)d_in[11], *rel_b1 = (const float*)d_in[12],
    *rel_w2 = (const float*)d_in[13], *rel_b2 = (const float*)d_in[14],
    *g_w0 = (const float*)d_in[15], *g_b0 = (const float*)d_in[16],
    *g_w1 = (const float*)d_in[17], *g_b1 = (const float*)d_in[18],
    *g_w2 = (const float*)d_in[19], *g_b2 = (const float*)d_in[20],
    *wih = (const float*)d_in[21], *whh = (const float*)d_in[22],
    *bih = (const float*)d_in[23], *bhh = (const float*)d_in[24],
    *r_w0 = (const float*)d_in[25], *r_b0 = (const float*)d_in[26],
    *r_w1 = (const float*)d_in[27], *r_b1 = (const float*)d_in[28],
    *r_w2 = (const float*)d_in[29], *r_b2 = (const float*)d_in[30],
    *c0 = (const float*)d_in[31];
  short* ws = (short*)d_ws;
  short* hist = ws + HISTOFF;
  const int iters_h = out_size / (BATCH * NN * NOUT);
  const size_t need = ((size_t)HISTOFF + (size_t)iters_h * BATCH * NN * HID) * sizeof(short);
  const bool defer = ws_size >= need && iters_h > 0;

  pack_kernel<<<dim3(328), dim3(64), 0, stream>>>(
      rel_w0, rel_w1, rel_w2, g_w0, g_w1, g_w2, wih, whh,
      r_w0, r_w1, r_w2, in_w1, in_w2, rel_b2, g_b2, ws);
  if (defer) {
    rrn_kernel<true><<<dim3(BATCH), dim3(BLOCK), 0, stream>>>(
        grids, iters, emb, in_w0, in_b0, in_b1, in_b2,
        rel_b0, rel_b1, g_b0, g_b1,
        bih, bhh, r_b0, r_b1, r_b2, c0, (const short*)ws, hist, (float*)d_out);
    readout_kernel<<<dim3(BATCH, iters_h), dim3(BLOCK), 0, stream>>>(
        hist, (const short*)ws, r_b0, r_b1, r_b2, (float*)d_out);
  } else {
    rrn_kernel<false><<<dim3(BATCH), dim3(BLOCK), 0, stream>>>(
        grids, iters, emb, in_w0, in_b0, in_b1, in_b2,
        rel_b0, rel_b1, g_b0, g_b1,
        bih, bhh, r_b0, r_b1, r_b2, c0, (const short*)ws, hist, (float*)d_out);
  }
}

// Round 19
// 778.860 us; speedup vs baseline: 2.3614x; 2.3614x over previous
//
#include <hip/hip_runtime.h>
#include <hip/hip_bf16.h>
#include <stdint.h>

typedef __attribute__((ext_vector_type(8))) short short8v;  // MFMA bf16 A/B frag
typedef __attribute__((ext_vector_type(4))) float float4v;  // MFMA C/D frag

#define DEVI __device__ __forceinline__

constexpr int BATCH = 256;
constexpr int NN   = 81;
constexpr int HID  = 96;
constexpr int NOUT = 9;
constexpr int BLOCK = 512;   // 8 waves = 2/SIMD; proven 124-VGPR no-spill config
constexpr int LDA = 100;   // f32 LDS row stride (floats)
constexpr int LDB = 104;   // bf16 LDS row stride (shorts): 208B, 16B-aligned

// LDS float offsets.
constexpr int OFF_XG = 0;        // f32 81x96   Xg (iteration-invariant)
constexpr int OFF_H0 = 7776;     // bf16 h buffer A
constexpr int OFF_H1 = 11988;    // bf16 h buffer B
constexpr int OFF_MS = 16200;    // f32 81x100 Msum (atomics)  / B2 bf16 scratch
constexpr int OFF_AP = 24300;    // f32 81x100 self-proj       / B1 bf16 scratch
constexpr int OFF_BV = 32400;    // f32 81x100 neighbor-proj
constexpr int SMEM_F = 40500;    // 162,000 B <= 163,840

// packed weights in d_ws (shorts): hi tiles [(ct*3+kt)*512 + lane*8 + j], lo at +ntiles*512.
constexpr int W_REL0A = 0;       // rel_w0 rows 0..95   (18 tiles)
constexpr int W_REL0B = 18432;   // rel_w0 rows 96..191 (18)
constexpr int W_REL1  = 36864;   // (18)
constexpr int W_COMB  = 55296;   // rel_w2 @ g_w0[96:192]  96x96 (18)
constexpr int W_G1    = 73728;   // (18)
constexpr int W_IHC   = 92160;   // g_w2 @ wih  96x384 (72)
constexpr int W_HH    = 165888;  // (72)
constexpr int W_R0    = 239616;  // (18)
constexpr int W_R1    = 258048;  // (18)
constexpr int W_R2    = 276480;  // 96x16, cols 9..15 zero (3)
constexpr int W_IN1   = 279552;  // (18)
constexpr int W_IN2   = 297984;  // (18)
constexpr int W_G0A   = 316416;  // g_w0 rows 0..95 (18) -> ends 334848
constexpr int BC2OFF  = 334848;  // f32[384]: g_b2 @ wih   (768 shorts)
constexpr int B3OFF   = 335616;  // f32[96]:  20*rel_b2 @ g_w0[96:]  (192 shorts)
constexpr int HISTOFF = 335808;  // bf16 hist[it][b][81*96], written iff DEFER

DEVI float sigm(float x)  { return 1.f / (1.f + __expf(-x)); }
DEVI float tanh_(float x) { return 1.f - 2.f / (__expf(2.f * x) + 1.f); }

DEVI short bfhi(float x) { union { float f; unsigned u; } v; v.f = x; return (short)(v.u >> 16); }
DEVI float fromBits(short s) { union { unsigned u; float f; } v; v.u = ((unsigned)(unsigned short)s) << 16; return v.f; }
DEVI short bfrne(float x) {
  union { float f; unsigned u; } v; v.f = x;
  unsigned r = v.u + 0x7fffu + ((v.u >> 16) & 1u);
  return (short)(r >> 16);
}
DEVI void split1(float x, short& h, short& l) { h = bfhi(x); l = bfrne(x - fromBits(h)); }

// f32 LDS row -> RNE bf16 fragment (for f32-resident inputs: MS, prologue AP)
DEVI void packFrag(const float* p, short8v& v) {
  const float4 a = *reinterpret_cast<const float4*>(p);
  const float4 b = *reinterpret_cast<const float4*>(p + 4);
  v[0] = bfrne(a.x); v[1] = bfrne(a.y); v[2] = bfrne(a.z); v[3] = bfrne(a.w);
  v[4] = bfrne(b.x); v[5] = bfrne(b.y); v[6] = bfrne(b.z); v[7] = bfrne(b.w);
}
// t0 = relu(Ap_row + Bv_row), RNE-packed (f32 inputs)
DEVI void packFragPair(const float* ap, const float* bp, short8v& v) {
  const float4 a0 = *reinterpret_cast<const float4*>(ap);
  const float4 a1 = *reinterpret_cast<const float4*>(ap + 4);
  const float4 b0 = *reinterpret_cast<const float4*>(bp);
  const float4 b1 = *reinterpret_cast<const float4*>(bp + 4);
  v[0] = bfrne(fmaxf(a0.x + b0.x, 0.f)); v[1] = bfrne(fmaxf(a0.y + b0.y, 0.f));
  v[2] = bfrne(fmaxf(a0.z + b0.z, 0.f)); v[3] = bfrne(fmaxf(a0.w + b0.w, 0.f));
  v[4] = bfrne(fmaxf(a1.x + b1.x, 0.f)); v[5] = bfrne(fmaxf(a1.y + b1.y, 0.f));
  v[6] = bfrne(fmaxf(a1.z + b1.z, 0.f)); v[7] = bfrne(fmaxf(a1.w + b1.w, 0.f));
}

// acc += A * (Wh + Wl): 2 MFMAs
DEVI float4v mfma2(short8v a, short8v bh, short8v bl, float4v acc) {
  acc = __builtin_amdgcn_mfma_f32_16x16x32_bf16(a, bh, acc, 0, 0, 0);
  acc = __builtin_amdgcn_mfma_f32_16x16x32_bf16(a, bl, acc, 0, 0, 0);
  return acc;
}

// e-th Sudoku peer of node n (order-free: message sum is permutation-invariant)
DEVI int nbr_of(int n, int e) {
  const int r = n / 9, c = n - 9 * r;
  if (e < 8)  { int cc = c + 1 + e;  if (cc >= 9) cc -= 9; return r * 9 + cc; }
  if (e < 16) { int rr = r + e - 7;  if (rr >= 9) rr -= 9; return rr * 9 + c; }
  const int q = e - 16, dr = 1 + (q >> 1), dc = 1 + (q & 1);
  const int rm = r % 3, cm = c % 3;
  int rr = r - rm + rm + dr; rr -= (rm + dr >= 3) ? 3 : 0;
  int cc = c - cm + cm + dc; cc -= (cm + dc >= 3) ? 3 : 0;
  return rr * 9 + cc;
}

// ---------------- weight pack kernel ----------------
__global__ __launch_bounds__(64)
void pack_kernel(const float* rel_w0, const float* rel_w1, const float* rel_w2,
                 const float* g_w0, const float* g_w1, const float* g_w2,
                 const float* wih, const float* whh,
                 const float* r_w0, const float* r_w1, const float* r_w2,
                 const float* in_w1, const float* in_w2,
                 const float* rel_b2, const float* g_b2, short* ws)
{
  const int lane = threadIdx.x;
  const int blk = blockIdx.x;
  if (blk == 327) {  // fused biases
    float* bc2 = reinterpret_cast<float*>(ws + BC2OFF);
    float* b3  = reinterpret_cast<float*>(ws + B3OFF);
    for (int c = lane; c < 384; c += 64) {
      float a = 0.f;
      for (int t = 0; t < 96; ++t) a += g_b2[t] * wih[t * 384 + c];
      bc2[c] = a;
    }
    for (int c = lane; c < 96; c += 64) {
      float a = 0.f;
      for (int t = 0; t < 96; ++t) a += 20.f * rel_b2[t] * g_w0[(96 + t) * 96 + c];
      b3[c] = a;
    }
    return;
  }
  const int starts[14] = {0,18,36,54,72,90,162,234,252,270,273,291,309,327};
  int mi = 0;
  while (blk >= starts[mi + 1]) ++mi;
  const int tt = blk - starts[mi];
  const int ntile = starts[mi + 1] - starts[mi];
  const int kt = tt % 3, ct = tt / 3;
  const int q = lane >> 4, r = lane & 15;
  int off, C = 96, row0 = 0;
  const float* src = nullptr;
  switch (mi) {
    case 0:  src = rel_w0; off = W_REL0A; break;
    case 1:  src = rel_w0; row0 = 96; off = W_REL0B; break;
    case 2:  src = rel_w1; off = W_REL1; break;
    case 3:  off = W_COMB; break;                      // computed product
    case 4:  src = g_w1; off = W_G1; break;
    case 5:  C = 384; off = W_IHC; break;              // computed product
    case 6:  src = whh; C = 384; off = W_HH; break;
    case 7:  src = r_w0; off = W_R0; break;
    case 8:  src = r_w1; off = W_R1; break;
    case 9:  src = r_w2; C = 9; off = W_R2; break;
    case 10: src = in_w1; off = W_IN1; break;
    case 11: src = in_w2; off = W_IN2; break;
    default: src = g_w0; off = W_G0A; break;
  }
  const int c = ct * 16 + r;
  short* hd = ws + off + tt * 512 + lane * 8;
  short* ld = hd + ntile * 512;
  if (mi == 3 || mi == 5) {   // W[k][c] = sum_t A[k][t] * B[t][c] in f32, then split
    const float* A  = (mi == 3) ? rel_w2 : g_w2;            // 96 x 96
    const float* Bm = (mi == 3) ? (g_w0 + 96 * 96) : wih;   // 96 x C2
    const int C2 = (mi == 3) ? 96 : 384;
    float acc[8] = {0,0,0,0,0,0,0,0};
    for (int t = 0; t < 96; ++t) {
      const float bv = Bm[t * C2 + c];
      #pragma unroll
      for (int j = 0; j < 8; ++j) acc[j] += A[(kt * 32 + q * 8 + j) * 96 + t] * bv;
    }
    #pragma unroll
    for (int j = 0; j < 8; ++j) { short h, l; split1(acc[j], h, l); hd[j] = h; ld[j] = l; }
  } else {
    #pragma unroll
    for (int j = 0; j < 8; ++j) {
      const int k = row0 + kt * 32 + q * 8 + j;
      float w = (c < C) ? src[k * C + c] : 0.f;
      short h, l; split1(w, h, l);
      hd[j] = h; ld[j] = l;
    }
  }
}

// -------- node-GEMM stage (r10-proven): 18 tasks (3 rtp x 6 ct), 2 row-subs --------
template<bool ABF, bool OBF, bool RELU, bool XGADD>
DEVI void stage96(float* sm, int aOff, const short* WS, int wOff, int wTiles,
                  const float* bias, float bscale, int dOff, int dstLDf,
                  int wave, int lane)
{
  const int rl = lane & 15, q = lane >> 4;
  const int plane = wTiles * 512;
  const short* asb = reinterpret_cast<const short*>(sm + aOff);
  short* dsb = reinterpret_cast<short*>(sm + dOff);
  float* dsf = sm + dOff;
  #pragma unroll 1
  for (int t = wave; t < 18; t += 8) {
    const int rtp = t % 3, ct = t / 3;
    short8v a2[2][3];
    #pragma unroll
    for (int sub = 0; sub < 2; ++sub) {
      const int row = rtp * 32 + sub * 16 + rl;
      if (ABF) {
        const short* ap = asb + row * LDB + q * 8;
        #pragma unroll
        for (int kt = 0; kt < 3; ++kt)
          a2[sub][kt] = *reinterpret_cast<const short8v*>(ap + kt * 32);
      } else {
        const float* ap = &sm[aOff + row * LDA + q * 8];
        #pragma unroll
        for (int kt = 0; kt < 3; ++kt) packFrag(ap + kt * 32, a2[sub][kt]);
      }
    }
    float4v acc0 = {0.f, 0.f, 0.f, 0.f}, acc1 = {0.f, 0.f, 0.f, 0.f};
    #pragma unroll
    for (int kt = 0; kt < 3; ++kt) {
      const short* bp = WS + wOff + (ct * 3 + kt) * 512 + lane * 8;
      const short8v bh = *reinterpret_cast<const short8v*>(bp);
      const short8v bl = *reinterpret_cast<const short8v*>(bp + plane);
      acc0 = mfma2(a2[0][kt], bh, bl, acc0);
      acc1 = mfma2(a2[1][kt], bh, bl, acc1);
    }
    const int col = ct * 16 + rl;
    #pragma unroll
    for (int sub = 0; sub < 2; ++sub) {
      #pragma unroll
      for (int j = 0; j < 4; ++j) {
        const int row = rtp * 32 + sub * 16 + q * 4 + j;
        if (row < NN) {
          float v = sub ? acc1[j] : acc0[j];
          if (bias)  v += bias[col] * bscale;
          if (XGADD) v += sm[OFF_XG + row * 96 + col];
          if (RELU)  v = fmaxf(v, 0.f);
          if (OBF) dsb[row * LDB + col] = bfrne(v);
          else     dsf[row * dstLDf + col] = v;
        }
      }
    }
  }
}

// ---------------- main kernel (r17 structure; phase-7 biases hoisted out of it-loop) ----------------
template<bool DEFER>
__global__ __launch_bounds__(BLOCK) __attribute__((amdgpu_waves_per_eu(1, 2)))
void rrn_kernel(const int* __restrict__ grids, const int* __restrict__ itersp,
                const float* __restrict__ emb, const float* __restrict__ in_w0,
                const float* __restrict__ in_b0, const float* __restrict__ in_b1,
                const float* __restrict__ in_b2,
                const float* __restrict__ rel_b0, const float* __restrict__ rel_b1,
                const float* __restrict__ g_b0, const float* __restrict__ g_b1,
                const float* __restrict__ bih, const float* __restrict__ bhh,
                const float* __restrict__ r_b0, const float* __restrict__ r_b1,
                const float* __restrict__ r_b2,
                const float* __restrict__ c0, const short* __restrict__ WS,
                short* __restrict__ hist, float* __restrict__ out)
{
  __shared__ float sm[SMEM_F];
  const int b = blockIdx.x, tid = threadIdx.x;
  const int wave = tid >> 6, lane = tid & 63;
  const int rl = lane & 15, q = lane >> 4;
  const int iters = itersp[0];

  // LSTM cell state in registers, cc-per-wave: wave w<6 owns col-tile cc=w. (r17-proven)
  float creg[6][4];
  #pragma unroll
  for (int rt = 0; rt < 6; ++rt)
    #pragma unroll
    for (int j = 0; j < 4; ++j) creg[rt][j] = 0.f;
  if (wave < 6) {
    #pragma unroll
    for (int rt = 0; rt < 6; ++rt) {
      #pragma unroll
      for (int j = 0; j < 4; ++j) {
        const int n = rt * 16 + q * 4 + j, col = wave * 16 + rl;
        creg[rt][j] = (n < NN) ? c0[(size_t)b * NN * HID + n * HID + col] : 0.f;
      }
    }
  }

  // phase-7 gate biases: wave-uniform AND iteration-invariant -> load ONCE (r18 lesson:
  // keep phase-7 live-state shape identical to r17; this adds only 4 persistent VGPRs)
  const float* bc2 = reinterpret_cast<const float*>(WS + BC2OFF);
  float bI = 0.f, bF = 0.f, bG = 0.f, bO = 0.f;
  if (wave < 6) {
    const int colh = wave * 16 + rl;
    bI = bih[colh]       + bhh[colh]       + bc2[colh];
    bF = bih[96 + colh]  + bhh[96 + colh]  + bc2[96 + colh];
    bG = bih[192 + colh] + bhh[192 + colh] + bc2[192 + colh];
    bO = bih[288 + colh] + bhh[288 + colh] + bc2[288 + colh];
  }

  // ---- prologue: embed L0 (VALU, K=16) -> AP f32, then MFMA stages ----
  for (int t = tid; t < NN * HID; t += BLOCK) {
    const int n = t / HID, col = t - n * HID;
    const int g = grids[b * NN + n];
    float acc = in_b0[col];
    #pragma unroll
    for (int k = 0; k < 16; ++k) acc += emb[g * 16 + k] * in_w0[k * HID + col];
    sm[OFF_AP + n * LDA + col] = fmaxf(acc, 0.f);
  }
  __syncthreads();
  stage96<false, true, true,  false>(sm, OFF_AP, WS, W_IN1, 18, in_b1, 1.f, OFF_MS, 0, wave, lane);
  __syncthreads();
  stage96<true,  true, false, false>(sm, OFF_MS, WS, W_IN2, 18, in_b2, 1.f, OFF_H0, 0, wave, lane);
  __syncthreads();
  stage96<true, false, false, false>(sm, OFF_H0, WS, W_G0A, 18, g_b0,  1.f, OFF_XG, 96, wave, lane);
  __syncthreads();

  const float* b3ptr = reinterpret_cast<const float*>(WS + B3OFF);

  for (int it = 0; it < iters; ++it) {
    const int hc = (it & 1) ? OFF_H1 : OFF_H0;   // current h (bf16)
    const int hn = (it & 1) ? OFF_H0 : OFF_H1;   // next h (bf16)

    // phase 1: zero Msum; Ap = h@rel_w0[0:96] + rel_b0 (f32); Bv = h@rel_w0[96:192] (f32)
    for (int i = tid; i < 8100; i += BLOCK) sm[OFF_MS + i] = 0.f;
    stage96<true, false, false, false>(sm, hc, WS, W_REL0A, 18, rel_b0, 1.f, OFF_AP, LDA, wave, lane);
    stage96<true, false, false, false>(sm, hc, WS, W_REL0B, 18, nullptr, 0.f, OFF_BV, LDA, wave, lane);
    __syncthreads();

    // phase 2: pair GEMM, 51 wave-private groups of 32 pair-rows; LDS atomics
    #pragma unroll 1
    for (int g2 = wave; g2 < 51; g2 += 8) {
      short8v a2[2][3];
      #pragma unroll
      for (int sub = 0; sub < 2; ++sub) {
        const int row = g2 * 32 + sub * 16 + rl;
        if (row < 1620) {
          const int n = row / 20, e = row - 20 * n, m = nbr_of(n, e);
          const float* ap = &sm[OFF_AP + n * LDA + q * 8];
          const float* bp = &sm[OFF_BV + m * LDA + q * 8];
          #pragma unroll
          for (int kt = 0; kt < 3; ++kt)
            packFragPair(ap + kt * 32, bp + kt * 32, a2[sub][kt]);
        } else {
          const short8v z = {0,0,0,0,0,0,0,0};
          #pragma unroll
          for (int kt = 0; kt < 3; ++kt) a2[sub][kt] = z;
        }
      }
      #pragma unroll 1
      for (int ct = 0; ct < 6; ++ct) {
        const float rb1c = rel_b1[ct * 16 + rl];
        float4v acc0 = {0,0,0,0}, acc1 = {0,0,0,0};
        #pragma unroll
        for (int kt = 0; kt < 3; ++kt) {
          const short* bp = WS + W_REL1 + (ct * 3 + kt) * 512 + lane * 8;
          const short8v bh = *reinterpret_cast<const short8v*>(bp);
          const short8v bl = *reinterpret_cast<const short8v*>(bp + 18 * 512);
          acc0 = mfma2(a2[0][kt], bh, bl, acc0);
          acc1 = mfma2(a2[1][kt], bh, bl, acc1);
        }
        const int col = ct * 16 + rl;
        #pragma unroll
        for (int sub = 0; sub < 2; ++sub) {
          const int r0 = g2 * 32 + sub * 16 + q * 4;  // 4 rows, same node (20%4==0)
          if (r0 < 1620) {
            const int node = r0 / 20;
            const float4v a = sub ? acc1 : acc0;
            const float s = fmaxf(a[0] + rb1c, 0.f) + fmaxf(a[1] + rb1c, 0.f)
                          + fmaxf(a[2] + rb1c, 0.f) + fmaxf(a[3] + rb1c, 0.f);
            atomicAdd(&sm[OFF_MS + node * LDA + col], s);
          }
        }
        __builtin_amdgcn_sched_barrier(0);
      }
    }
    __syncthreads();

    // ph3' (fused): g0 = relu(Xg + Msum@W_COMB + b3) -> B1 bf16 (AP region)
    stage96<false, true, true, true>(sm, OFF_MS, WS, W_COMB, 18, b3ptr, 1.f, OFF_AP, 0, wave, lane);
    __syncthreads();
    // ph5: g1 = relu(g0@g_w1 + g_b1) -> B2 bf16 (MS region)
    stage96<true, true, true, false>(sm, OFF_AP, WS, W_G1, 18, g_b1, 1.f, OFF_MS, 0, wave, lane);
    __syncthreads();

    // phase 7 (r17-proven 6-wave shape): gates = g1@W_IHC + h@whh + hoisted biases
    if (wave < 6) {
      const int colh = wave * 16 + rl;
      const short* xs = reinterpret_cast<const short*>(sm + OFF_MS);  // g1
      const short* hs = reinterpret_cast<const short*>(sm + hc);
      short* hnp = reinterpret_cast<short*>(sm + hn);
      short* hg = hist + (size_t)(it * BATCH + b) * (NN * HID);
      #pragma unroll
      for (int rt = 0; rt < 6; ++rt) {
        const int row = rt * 16 + rl;
        short8v af[6];
        #pragma unroll
        for (int kt = 0; kt < 3; ++kt)
          af[kt] = *reinterpret_cast<const short8v*>(xs + row * LDB + kt * 32 + q * 8);
        #pragma unroll
        for (int kt = 3; kt < 6; ++kt)
          af[kt] = *reinterpret_cast<const short8v*>(hs + row * LDB + (kt - 3) * 32 + q * 8);
        float4v ga[4];
        #pragma unroll
        for (int gate = 0; gate < 4; ++gate) {
          const int ct = gate * 6 + wave;
          float4v acc = {0.f, 0.f, 0.f, 0.f};
          #pragma unroll
          for (int kt = 0; kt < 3; ++kt) {
            const short* bp = WS + W_IHC + (ct * 3 + kt) * 512 + lane * 8;
            acc = mfma2(af[kt], *reinterpret_cast<const short8v*>(bp),
                        *reinterpret_cast<const short8v*>(bp + 72 * 512), acc);
          }
          __builtin_amdgcn_sched_barrier(0);
          #pragma unroll
          for (int kt = 3; kt < 6; ++kt) {
            const short* bp = WS + W_HH + (ct * 3 + kt - 3) * 512 + lane * 8;
            acc = mfma2(af[kt], *reinterpret_cast<const short8v*>(bp),
                        *reinterpret_cast<const short8v*>(bp + 72 * 512), acc);
          }
          ga[gate] = acc;
          __builtin_amdgcn_sched_barrier(0);
        }
        #pragma unroll
        for (int j = 0; j < 4; ++j) {
          const int n = rt * 16 + q * 4 + j;
          const float gi = ga[0][j] + bI;
          const float gf = ga[1][j] + bF;
          const float gg = ga[2][j] + bG;
          const float go = ga[3][j] + bO;
          const float c2 = sigm(gf) * creg[rt][j] + sigm(gi) * tanh_(gg);
          creg[rt][j] = c2;
          if (n < NN) {
            const short hb = bfrne(sigm(go) * tanh_(c2));
            hnp[n * LDB + colh] = hb;
            if (DEFER) hg[n * HID + colh] = hb;
          }
        }
      }
    }
    __syncthreads();

    if constexpr (!DEFER) {
      stage96<true, true, true, false>(sm, hn, WS, W_R0, 18, r_b0, 1.f, OFF_AP, 0, wave, lane);
      __syncthreads();
      stage96<true, true, true, false>(sm, OFF_AP, WS, W_R1, 18, r_b1, 1.f, OFF_MS, 0, wave, lane);
      __syncthreads();
      if (wave < 6) {
        const int rt6 = wave;
        const short* asb = reinterpret_cast<const short*>(sm + OFF_MS);
        const int row = rt6 * 16 + rl;
        short8v a2[3];
        #pragma unroll
        for (int kt = 0; kt < 3; ++kt)
          a2[kt] = *reinterpret_cast<const short8v*>(asb + row * LDB + kt * 32 + q * 8);
        float4v acc = {0,0,0,0};
        #pragma unroll
        for (int kt = 0; kt < 3; ++kt) {
          const short* bp = WS + W_R2 + kt * 512 + lane * 8;
          acc = mfma2(a2[kt], *reinterpret_cast<const short8v*>(bp),
                      *reinterpret_cast<const short8v*>(bp + 3 * 512), acc);
        }
        if (rl < NOUT) {
          float* op = out + ((size_t)it * BATCH + b) * NN * NOUT;
          #pragma unroll
          for (int j = 0; j < 4; ++j) {
            const int r2 = rt6 * 16 + q * 4 + j;
            if (r2 < NN) op[r2 * NOUT + rl] = acc[j] + r_b2[rl];
          }
        }
      }
      __syncthreads();
    }
  }
}

// ---------------- deferred readout kernel: grid (BATCH, iters), 53.7KB LDS -> 3 blk/CU ----------------
constexpr int RO_H  = 0;
constexpr int RO_B1 = 4212;
constexpr int RO_B2 = 8424;
constexpr int RO_F  = 13416;  // + pad so row-95 fragment reads stay in-bounds

__global__ __launch_bounds__(BLOCK)
void readout_kernel(const short* __restrict__ hist, const short* __restrict__ WS,
                    const float* __restrict__ r_b0, const float* __restrict__ r_b1,
                    const float* __restrict__ r_b2, float* __restrict__ out)
{
  __shared__ float sm[RO_F];
  const int b = blockIdx.x, it = blockIdx.y;
  const int tid = threadIdx.x, wave = tid >> 6, lane = tid & 63;
  const int rl = lane & 15, q = lane >> 4;

  short* hx = reinterpret_cast<short*>(sm + RO_H);
  const short* src = hist + (size_t)(it * BATCH + b) * (NN * HID);
  for (int t = tid; t < NN * HID; t += BLOCK) {
    const int n = t / HID, c = t - n * HID;
    hx[n * LDB + c] = src[t];
  }
  __syncthreads();
  stage96<true, true, true, false>(sm, RO_H,  WS, W_R0, 18, r_b0, 1.f, RO_B1, 0, wave, lane);
  __syncthreads();
  stage96<true, true, true, false>(sm, RO_B1, WS, W_R1, 18, r_b1, 1.f, RO_B2, 0, wave, lane);
  __syncthreads();
  if (wave < 6) {
    const int rt6 = wave;
    const short* asb = reinterpret_cast<const short*>(sm + RO_B2);
    const int row = rt6 * 16 + rl;
    short8v a2[3];
    #pragma unroll
    for (int kt = 0; kt < 3; ++kt)
      a2[kt] = *reinterpret_cast<const short8v*>(asb + row * LDB + kt * 32 + q * 8);
    float4v acc = {0,0,0,0};
    #pragma unroll
    for (int kt = 0; kt < 3; ++kt) {
      const short* bp = WS + W_R2 + kt * 512 + lane * 8;
      acc = mfma2(a2[kt], *reinterpret_cast<const short8v*>(bp),
                  *reinterpret_cast<const short8v*>(bp + 3 * 512), acc);
    }
    if (rl < NOUT) {
      float* op = out + ((size_t)it * BATCH + b) * NN * NOUT;
      #pragma unroll
      for (int j = 0; j < 4; ++j) {
        const int r2 = rt6 * 16 + q * 4 + j;
        if (r2 < NN) op[r2 * NOUT + rl] = acc[j] + r_b2[rl];
      }
    }
  }
}

extern "C" void kernel_launch(void* const* d_in, const int* in_sizes, int n_in,
                              void* d_out, int out_size, void* d_ws, size_t ws_size,
                              hipStream_t stream) {
  (void)in_sizes; (void)n_in;
  const int* grids = (const int*)d_in[0];
  const int* iters = (const int*)d_in[1];
  const float *emb = (const float*)d_in[2],
    *in_w0 = (const float*)d_in[3],  *in_b0 = (const float*)d_in[4],
    *in_w1 = (const float*)d_in[5],  *in_b1 = (const float*)d_in[6],
    *in_w2 = (const float*)d_in[7],  *in_b2 = (const float*)d_in[8],
    *rel_w0 = (const float*)d_in[9],  *rel_b0 = (const float*)d_in[10],
    *rel_w1 = (const float*)d_in[11], *rel_b1 = (const float*)d_in[12],
    *rel_w2 = (const float*)d_in[13], *rel_b2 = (const float*)d_in[14],
    *g_w0 = (const float*)d_in[15], *g_b0 = (const float*)d_in[16],
    *g_w1 = (const float*)d_in[17], *g_b1 = (const float*)d_in[18],
    *g_w2 = (const float*)d_in[19], *g_b2 = (const float*)d_in[20],
    *wih = (const float*)d_in[21], *whh = (const float*)d_in[22],
    *bih = (const float*)d_in[23], *bhh = (const float*)d_in[24],
    *r_w0 = (const float*)d_in[25], *r_b0 = (const float*)d_in[26],
    *r_w1 = (const float*)d_in[27], *r_b1 = (const float*)d_in[28],
    *r_w2 = (const float*)d_in[29], *r_b2 = (const float*)d_in[30],
    *c0 = (const float*)d_in[31];
  short* ws = (short*)d_ws;
  short* hist = ws + HISTOFF;
  const int iters_h = out_size / (BATCH * NN * NOUT);
  const size_t need = ((size_t)HISTOFF + (size_t)iters_h * BATCH * NN * HID) * sizeof(short);
  const bool defer = ws_size >= need && iters_h > 0;

  pack_kernel<<<dim3(328), dim3(64), 0, stream>>>(
      rel_w0, rel_w1, rel_w2, g_w0, g_w1, g_w2, wih, whh,
      r_w0, r_w1, r_w2, in_w1, in_w2, rel_b2, g_b2, ws);
  if (defer) {
    rrn_kernel<true><<<dim3(BATCH), dim3(BLOCK), 0, stream>>>(
        grids, iters, emb, in_w0, in_b0, in_b1, in_b2,
        rel_b0, rel_b1, g_b0, g_b1,
        bih, bhh, r_b0, r_b1, r_b2, c0, (const short*)ws, hist, (float*)d_out);
    readout_kernel<<<dim3(BATCH, iters_h), dim3(BLOCK), 0, stream>>>(
        hist, (const short*)ws, r_b0, r_b1, r_b2, (float*)d_out);
  } else {
    rrn_kernel<false><<<dim3(BATCH), dim3(BLOCK), 0, stream>>>(
        grids, iters, emb, in_w0, in_b0, in_b1, in_b2,
        rel_b0, rel_b1, g_b0, g_b1,
        bih, bhh, r_b0, r_b1, r_b2, c0, (const short*)ws, hist, (float*)d_out);
  }
}

// Round 20
// 775.802 us; speedup vs baseline: 2.3707x; 1.0039x over previous
//
#include <hip/hip_runtime.h>
#include <hip/hip_bf16.h>
#include <stdint.h>

typedef __attribute__((ext_vector_type(8))) short short8v;  // MFMA bf16 A/B frag
typedef __attribute__((ext_vector_type(4))) float float4v;  // MFMA C/D frag

#define DEVI __device__ __forceinline__

constexpr int BATCH = 256;
constexpr int NN   = 81;
constexpr int HID  = 96;
constexpr int NOUT = 9;
constexpr int BLOCK = 512;   // 8 waves = 2/SIMD; proven 124-128-VGPR no-spill config
constexpr int LDA = 100;   // f32 LDS row stride (floats)
constexpr int LDB = 104;   // bf16 LDS row stride (shorts): 208B, 16B-aligned

// LDS float offsets.
constexpr int OFF_XG = 0;        // f32 81x96   Xg (iteration-invariant)
constexpr int OFF_H0 = 7776;     // bf16 h buffer A
constexpr int OFF_H1 = 11988;    // bf16 h buffer B
constexpr int OFF_MS = 16200;    // f32 81x100 Msum (atomics)  / B2 bf16 scratch
constexpr int OFF_AP = 24300;    // f32 81x100 self-proj       / B1 bf16 scratch
constexpr int OFF_BV = 32400;    // f32 81x100 neighbor-proj
constexpr int SMEM_F = 40500;    // 162,000 B <= 163,840

// packed weights in d_ws (shorts): hi tiles [(ct*3+kt)*512 + lane*8 + j], lo at +ntiles*512.
constexpr int W_REL0A = 0;       // rel_w0 rows 0..95   (18 tiles)
constexpr int W_REL0B = 18432;   // rel_w0 rows 96..191 (18)
constexpr int W_REL1  = 36864;   // (18)
constexpr int W_COMB  = 55296;   // rel_w2 @ g_w0[96:192]  96x96 (18)
constexpr int W_G1    = 73728;   // (18)
constexpr int W_IHC   = 92160;   // g_w2 @ wih  96x384 (72)
constexpr int W_HH    = 165888;  // (72)
constexpr int W_R0    = 239616;  // (18)
constexpr int W_R1    = 258048;  // (18)
constexpr int W_R2    = 276480;  // 96x16, cols 9..15 zero (3)
constexpr int W_IN1   = 279552;  // (18)
constexpr int W_IN2   = 297984;  // (18)
constexpr int W_G0A   = 316416;  // g_w0 rows 0..95 (18) -> ends 334848
constexpr int BC2OFF  = 334848;  // f32[384]: g_b2 @ wih   (768 shorts)
constexpr int B3OFF   = 335616;  // f32[96]:  20*rel_b2 @ g_w0[96:]  (192 shorts)
constexpr int HISTOFF = 335808;  // bf16 hist[it][b][81*96], written iff DEFER

DEVI float sigm(float x)  { return 1.f / (1.f + __expf(-x)); }
DEVI float tanh_(float x) { return 1.f - 2.f / (__expf(2.f * x) + 1.f); }

DEVI short bfhi(float x) { union { float f; unsigned u; } v; v.f = x; return (short)(v.u >> 16); }
DEVI float fromBits(short s) { union { unsigned u; float f; } v; v.u = ((unsigned)(unsigned short)s) << 16; return v.f; }
DEVI short bfrne(float x) {
  union { float f; unsigned u; } v; v.f = x;
  unsigned r = v.u + 0x7fffu + ((v.u >> 16) & 1u);
  return (short)(r >> 16);
}
DEVI void split1(float x, short& h, short& l) { h = bfhi(x); l = bfrne(x - fromBits(h)); }

// RNE f32->bf16 via HIP cast: same bits as bfrne for finite values, but the compiler
// can fuse pairs into v_cvt_pk_bf16_f32 (1 instr / 2 elems vs ~3 instr / elem).
DEVI short f2bs(float x) {
  __hip_bfloat16 h = __float2bfloat16(x);
  return *reinterpret_cast<const short*>(&h);
}

// f32 LDS row -> RNE bf16 fragment (for f32-resident inputs: MS, prologue AP)
DEVI void packFrag(const float* p, short8v& v) {
  const float4 a = *reinterpret_cast<const float4*>(p);
  const float4 b = *reinterpret_cast<const float4*>(p + 4);
  v[0] = f2bs(a.x); v[1] = f2bs(a.y); v[2] = f2bs(a.z); v[3] = f2bs(a.w);
  v[4] = f2bs(b.x); v[5] = f2bs(b.y); v[6] = f2bs(b.z); v[7] = f2bs(b.w);
}
// t0 = relu(Ap_row + Bv_row), RNE-packed (f32 inputs)
DEVI void packFragPair(const float* ap, const float* bp, short8v& v) {
  const float4 a0 = *reinterpret_cast<const float4*>(ap);
  const float4 a1 = *reinterpret_cast<const float4*>(ap + 4);
  const float4 b0 = *reinterpret_cast<const float4*>(bp);
  const float4 b1 = *reinterpret_cast<const float4*>(bp + 4);
  v[0] = f2bs(fmaxf(a0.x + b0.x, 0.f)); v[1] = f2bs(fmaxf(a0.y + b0.y, 0.f));
  v[2] = f2bs(fmaxf(a0.z + b0.z, 0.f)); v[3] = f2bs(fmaxf(a0.w + b0.w, 0.f));
  v[4] = f2bs(fmaxf(a1.x + b1.x, 0.f)); v[5] = f2bs(fmaxf(a1.y + b1.y, 0.f));
  v[6] = f2bs(fmaxf(a1.z + b1.z, 0.f)); v[7] = f2bs(fmaxf(a1.w + b1.w, 0.f));
}

// acc += A * (Wh + Wl): 2 MFMAs
DEVI float4v mfma2(short8v a, short8v bh, short8v bl, float4v acc) {
  acc = __builtin_amdgcn_mfma_f32_16x16x32_bf16(a, bh, acc, 0, 0, 0);
  acc = __builtin_amdgcn_mfma_f32_16x16x32_bf16(a, bl, acc, 0, 0, 0);
  return acc;
}

// e-th Sudoku peer of node n (order-free: message sum is permutation-invariant)
DEVI int nbr_of(int n, int e) {
  const int r = n / 9, c = n - 9 * r;
  if (e < 8)  { int cc = c + 1 + e;  if (cc >= 9) cc -= 9; return r * 9 + cc; }
  if (e < 16) { int rr = r + e - 7;  if (rr >= 9) rr -= 9; return rr * 9 + c; }
  const int q = e - 16, dr = 1 + (q >> 1), dc = 1 + (q & 1);
  const int rm = r % 3, cm = c % 3;
  int rr = r - rm + rm + dr; rr -= (rm + dr >= 3) ? 3 : 0;
  int cc = c - cm + cm + dc; cc -= (cm + dc >= 3) ? 3 : 0;
  return rr * 9 + cc;
}

// ---------------- weight pack kernel (bit-identical weights to r19) ----------------
__global__ __launch_bounds__(64)
void pack_kernel(const float* rel_w0, const float* rel_w1, const float* rel_w2,
                 const float* g_w0, const float* g_w1, const float* g_w2,
                 const float* wih, const float* whh,
                 const float* r_w0, const float* r_w1, const float* r_w2,
                 const float* in_w1, const float* in_w2,
                 const float* rel_b2, const float* g_b2, short* ws)
{
  const int lane = threadIdx.x;
  const int blk = blockIdx.x;
  if (blk == 327) {  // fused biases
    float* bc2 = reinterpret_cast<float*>(ws + BC2OFF);
    float* b3  = reinterpret_cast<float*>(ws + B3OFF);
    for (int c = lane; c < 384; c += 64) {
      float a = 0.f;
      for (int t = 0; t < 96; ++t) a += g_b2[t] * wih[t * 384 + c];
      bc2[c] = a;
    }
    for (int c = lane; c < 96; c += 64) {
      float a = 0.f;
      for (int t = 0; t < 96; ++t) a += 20.f * rel_b2[t] * g_w0[(96 + t) * 96 + c];
      b3[c] = a;
    }
    return;
  }
  const int starts[14] = {0,18,36,54,72,90,162,234,252,270,273,291,309,327};
  int mi = 0;
  while (blk >= starts[mi + 1]) ++mi;
  const int tt = blk - starts[mi];
  const int ntile = starts[mi + 1] - starts[mi];
  const int kt = tt % 3, ct = tt / 3;
  const int q = lane >> 4, r = lane & 15;
  int off, C = 96, row0 = 0;
  const float* src = nullptr;
  switch (mi) {
    case 0:  src = rel_w0; off = W_REL0A; break;
    case 1:  src = rel_w0; row0 = 96; off = W_REL0B; break;
    case 2:  src = rel_w1; off = W_REL1; break;
    case 3:  off = W_COMB; break;                      // computed product
    case 4:  src = g_w1; off = W_G1; break;
    case 5:  C = 384; off = W_IHC; break;              // computed product
    case 6:  src = whh; C = 384; off = W_HH; break;
    case 7:  src = r_w0; off = W_R0; break;
    case 8:  src = r_w1; off = W_R1; break;
    case 9:  src = r_w2; C = 9; off = W_R2; break;
    case 10: src = in_w1; off = W_IN1; break;
    case 11: src = in_w2; off = W_IN2; break;
    default: src = g_w0; off = W_G0A; break;
  }
  const int c = ct * 16 + r;
  short* hd = ws + off + tt * 512 + lane * 8;
  short* ld = hd + ntile * 512;
  if (mi == 3 || mi == 5) {   // W[k][c] = sum_t A[k][t] * B[t][c] in f32, then split
    const float* A  = (mi == 3) ? rel_w2 : g_w2;            // 96 x 96
    const float* Bm = (mi == 3) ? (g_w0 + 96 * 96) : wih;   // 96 x C2
    const int C2 = (mi == 3) ? 96 : 384;
    float acc[8] = {0,0,0,0,0,0,0,0};
    for (int t = 0; t < 96; ++t) {
      const float bv = Bm[t * C2 + c];
      #pragma unroll
      for (int j = 0; j < 8; ++j) acc[j] += A[(kt * 32 + q * 8 + j) * 96 + t] * bv;
    }
    #pragma unroll
    for (int j = 0; j < 8; ++j) { short h, l; split1(acc[j], h, l); hd[j] = h; ld[j] = l; }
  } else {
    #pragma unroll
    for (int j = 0; j < 8; ++j) {
      const int k = row0 + kt * 32 + q * 8 + j;
      float w = (c < C) ? src[k * C + c] : 0.f;
      short h, l; split1(w, h, l);
      hd[j] = h; ld[j] = l;
    }
  }
}

// -------- node-GEMM stage (r10-proven): 18 tasks (3 rtp x 6 ct), 2 row-subs --------
template<bool ABF, bool OBF, bool RELU, bool XGADD>
DEVI void stage96(float* sm, int aOff, const short* WS, int wOff, int wTiles,
                  const float* bias, float bscale, int dOff, int dstLDf,
                  int wave, int lane)
{
  const int rl = lane & 15, q = lane >> 4;
  const int plane = wTiles * 512;
  const short* asb = reinterpret_cast<const short*>(sm + aOff);
  short* dsb = reinterpret_cast<short*>(sm + dOff);
  float* dsf = sm + dOff;
  #pragma unroll 1
  for (int t = wave; t < 18; t += 8) {
    const int rtp = t % 3, ct = t / 3;
    short8v a2[2][3];
    #pragma unroll
    for (int sub = 0; sub < 2; ++sub) {
      const int row = rtp * 32 + sub * 16 + rl;
      if (ABF) {
        const short* ap = asb + row * LDB + q * 8;
        #pragma unroll
        for (int kt = 0; kt < 3; ++kt)
          a2[sub][kt] = *reinterpret_cast<const short8v*>(ap + kt * 32);
      } else {
        const float* ap = &sm[aOff + row * LDA + q * 8];
        #pragma unroll
        for (int kt = 0; kt < 3; ++kt) packFrag(ap + kt * 32, a2[sub][kt]);
      }
    }
    float4v acc0 = {0.f, 0.f, 0.f, 0.f}, acc1 = {0.f, 0.f, 0.f, 0.f};
    #pragma unroll
    for (int kt = 0; kt < 3; ++kt) {
      const short* bp = WS + wOff + (ct * 3 + kt) * 512 + lane * 8;
      const short8v bh = *reinterpret_cast<const short8v*>(bp);
      const short8v bl = *reinterpret_cast<const short8v*>(bp + plane);
      acc0 = mfma2(a2[0][kt], bh, bl, acc0);
      acc1 = mfma2(a2[1][kt], bh, bl, acc1);
    }
    const int col = ct * 16 + rl;
    #pragma unroll
    for (int sub = 0; sub < 2; ++sub) {
      #pragma unroll
      for (int j = 0; j < 4; ++j) {
        const int row = rtp * 32 + sub * 16 + q * 4 + j;
        if (row < NN) {
          float v = sub ? acc1[j] : acc0[j];
          if (bias)  v += bias[col] * bscale;
          if (XGADD) v += sm[OFF_XG + row * 96 + col];
          if (RELU)  v = fmaxf(v, 0.f);
          if (OBF) dsb[row * LDB + col] = f2bs(v);
          else     dsf[row * dstLDf + col] = v;
        }
      }
    }
  }
}

// ---------------- main kernel (r19 structure; cvt-pack via casts) ----------------
template<bool DEFER>
__global__ __launch_bounds__(BLOCK) __attribute__((amdgpu_waves_per_eu(1, 2)))
void rrn_kernel(const int* __restrict__ grids, const int* __restrict__ itersp,
                const float* __restrict__ emb, const float* __restrict__ in_w0,
                const float* __restrict__ in_b0, const float* __restrict__ in_b1,
                const float* __restrict__ in_b2,
                const float* __restrict__ rel_b0, const float* __restrict__ rel_b1,
                const float* __restrict__ g_b0, const float* __restrict__ g_b1,
                const float* __restrict__ bih, const float* __restrict__ bhh,
                const float* __restrict__ r_b0, const float* __restrict__ r_b1,
                const float* __restrict__ r_b2,
                const float* __restrict__ c0, const short* __restrict__ WS,
                short* __restrict__ hist, float* __restrict__ out)
{
  __shared__ float sm[SMEM_F];
  const int b = blockIdx.x, tid = threadIdx.x;
  const int wave = tid >> 6, lane = tid & 63;
  const int rl = lane & 15, q = lane >> 4;
  const int iters = itersp[0];

  // LSTM cell state in registers, cc-per-wave: wave w<6 owns col-tile cc=w.
  float creg[6][4];
  #pragma unroll
  for (int rt = 0; rt < 6; ++rt)
    #pragma unroll
    for (int j = 0; j < 4; ++j) creg[rt][j] = 0.f;
  if (wave < 6) {
    #pragma unroll
    for (int rt = 0; rt < 6; ++rt) {
      #pragma unroll
      for (int j = 0; j < 4; ++j) {
        const int n = rt * 16 + q * 4 + j, col = wave * 16 + rl;
        creg[rt][j] = (n < NN) ? c0[(size_t)b * NN * HID + n * HID + col] : 0.f;
      }
    }
  }

  // phase-7 gate biases: wave-uniform AND iteration-invariant -> load ONCE
  const float* bc2 = reinterpret_cast<const float*>(WS + BC2OFF);
  float bI = 0.f, bF = 0.f, bG = 0.f, bO = 0.f;
  if (wave < 6) {
    const int colh = wave * 16 + rl;
    bI = bih[colh]       + bhh[colh]       + bc2[colh];
    bF = bih[96 + colh]  + bhh[96 + colh]  + bc2[96 + colh];
    bG = bih[192 + colh] + bhh[192 + colh] + bc2[192 + colh];
    bO = bih[288 + colh] + bhh[288 + colh] + bc2[288 + colh];
  }

  // ---- prologue: embed L0 (VALU, K=16) -> AP f32, then MFMA stages ----
  for (int t = tid; t < NN * HID; t += BLOCK) {
    const int n = t / HID, col = t - n * HID;
    const int g = grids[b * NN + n];
    float acc = in_b0[col];
    #pragma unroll
    for (int k = 0; k < 16; ++k) acc += emb[g * 16 + k] * in_w0[k * HID + col];
    sm[OFF_AP + n * LDA + col] = fmaxf(acc, 0.f);
  }
  __syncthreads();
  stage96<false, true, true,  false>(sm, OFF_AP, WS, W_IN1, 18, in_b1, 1.f, OFF_MS, 0, wave, lane);
  __syncthreads();
  stage96<true,  true, false, false>(sm, OFF_MS, WS, W_IN2, 18, in_b2, 1.f, OFF_H0, 0, wave, lane);
  __syncthreads();
  stage96<true, false, false, false>(sm, OFF_H0, WS, W_G0A, 18, g_b0,  1.f, OFF_XG, 96, wave, lane);
  __syncthreads();

  const float* b3ptr = reinterpret_cast<const float*>(WS + B3OFF);

  for (int it = 0; it < iters; ++it) {
    const int hc = (it & 1) ? OFF_H1 : OFF_H0;   // current h (bf16)
    const int hn = (it & 1) ? OFF_H0 : OFF_H1;   // next h (bf16)

    // phase 1: zero Msum; Ap = h@rel_w0[0:96] + rel_b0 (f32); Bv = h@rel_w0[96:192] (f32)
    for (int i = tid; i < 8100; i += BLOCK) sm[OFF_MS + i] = 0.f;
    stage96<true, false, false, false>(sm, hc, WS, W_REL0A, 18, rel_b0, 1.f, OFF_AP, LDA, wave, lane);
    stage96<true, false, false, false>(sm, hc, WS, W_REL0B, 18, nullptr, 0.f, OFF_BV, LDA, wave, lane);
    __syncthreads();

    // phase 2: pair GEMM, 51 wave-private groups of 32 pair-rows; LDS atomics
    #pragma unroll 1
    for (int g2 = wave; g2 < 51; g2 += 8) {
      short8v a2[2][3];
      #pragma unroll
      for (int sub = 0; sub < 2; ++sub) {
        const int row = g2 * 32 + sub * 16 + rl;
        if (row < 1620) {
          const int n = row / 20, e = row - 20 * n, m = nbr_of(n, e);
          const float* ap = &sm[OFF_AP + n * LDA + q * 8];
          const float* bp = &sm[OFF_BV + m * LDA + q * 8];
          #pragma unroll
          for (int kt = 0; kt < 3; ++kt)
            packFragPair(ap + kt * 32, bp + kt * 32, a2[sub][kt]);
        } else {
          const short8v z = {0,0,0,0,0,0,0,0};
          #pragma unroll
          for (int kt = 0; kt < 3; ++kt) a2[sub][kt] = z;
        }
      }
      #pragma unroll 1
      for (int ct = 0; ct < 6; ++ct) {
        const float rb1c = rel_b1[ct * 16 + rl];
        float4v acc0 = {0,0,0,0}, acc1 = {0,0,0,0};
        #pragma unroll
        for (int kt = 0; kt < 3; ++kt) {
          const short* bp = WS + W_REL1 + (ct * 3 + kt) * 512 + lane * 8;
          const short8v bh = *reinterpret_cast<const short8v*>(bp);
          const short8v bl = *reinterpret_cast<const short8v*>(bp + 18 * 512);
          acc0 = mfma2(a2[0][kt], bh, bl, acc0);
          acc1 = mfma2(a2[1][kt], bh, bl, acc1);
        }
        const int col = ct * 16 + rl;
        #pragma unroll
        for (int sub = 0; sub < 2; ++sub) {
          const int r0 = g2 * 32 + sub * 16 + q * 4;  // 4 rows, same node (20%4==0)
          if (r0 < 1620) {
            const int node = r0 / 20;
            const float4v a = sub ? acc1 : acc0;
            const float s = fmaxf(a[0] + rb1c, 0.f) + fmaxf(a[1] + rb1c, 0.f)
                          + fmaxf(a[2] + rb1c, 0.f) + fmaxf(a[3] + rb1c, 0.f);
            atomicAdd(&sm[OFF_MS + node * LDA + col], s);
          }
        }
        __builtin_amdgcn_sched_barrier(0);
      }
    }
    __syncthreads();

    // ph3' (fused): g0 = relu(Xg + Msum@W_COMB + b3) -> B1 bf16 (AP region)
    stage96<false, true, true, true>(sm, OFF_MS, WS, W_COMB, 18, b3ptr, 1.f, OFF_AP, 0, wave, lane);
    __syncthreads();
    // ph5: g1 = relu(g0@g_w1 + g_b1) -> B2 bf16 (MS region)
    stage96<true, true, true, false>(sm, OFF_AP, WS, W_G1, 18, g_b1, 1.f, OFF_MS, 0, wave, lane);
    __syncthreads();

    // phase 7 (r17-proven 6-wave shape): gates = g1@W_IHC + h@whh + hoisted biases
    if (wave < 6) {
      const int colh = wave * 16 + rl;
      const short* xs = reinterpret_cast<const short*>(sm + OFF_MS);  // g1
      const short* hs = reinterpret_cast<const short*>(sm + hc);
      short* hnp = reinterpret_cast<short*>(sm + hn);
      short* hg = hist + (size_t)(it * BATCH + b) * (NN * HID);
      #pragma unroll
      for (int rt = 0; rt < 6; ++rt) {
        const int row = rt * 16 + rl;
        short8v af[6];
        #pragma unroll
        for (int kt = 0; kt < 3; ++kt)
          af[kt] = *reinterpret_cast<const short8v*>(xs + row * LDB + kt * 32 + q * 8);
        #pragma unroll
        for (int kt = 3; kt < 6; ++kt)
          af[kt] = *reinterpret_cast<const short8v*>(hs + row * LDB + (kt - 3) * 32 + q * 8);
        float4v ga[4];
        #pragma unroll
        for (int gate = 0; gate < 4; ++gate) {
          const int ct = gate * 6 + wave;
          float4v acc = {0.f, 0.f, 0.f, 0.f};
          #pragma unroll
          for (int kt = 0; kt < 3; ++kt) {
            const short* bp = WS + W_IHC + (ct * 3 + kt) * 512 + lane * 8;
            acc = mfma2(af[kt], *reinterpret_cast<const short8v*>(bp),
                        *reinterpret_cast<const short8v*>(bp + 72 * 512), acc);
          }
          __builtin_amdgcn_sched_barrier(0);
          #pragma unroll
          for (int kt = 3; kt < 6; ++kt) {
            const short* bp = WS + W_HH + (ct * 3 + kt - 3) * 512 + lane * 8;
            acc = mfma2(af[kt], *reinterpret_cast<const short8v*>(bp),
                        *reinterpret_cast<const short8v*>(bp + 72 * 512), acc);
          }
          ga[gate] = acc;
          __builtin_amdgcn_sched_barrier(0);
        }
        #pragma unroll
        for (int j = 0; j < 4; ++j) {
          const int n = rt * 16 + q * 4 + j;
          const float gi = ga[0][j] + bI;
          const float gf = ga[1][j] + bF;
          const float gg = ga[2][j] + bG;
          const float go = ga[3][j] + bO;
          const float c2 = sigm(gf) * creg[rt][j] + sigm(gi) * tanh_(gg);
          creg[rt][j] = c2;
          if (n < NN) {
            const short hb = f2bs(sigm(go) * tanh_(c2));
            hnp[n * LDB + colh] = hb;
            if (DEFER) hg[n * HID + colh] = hb;
          }
        }
      }
    }
    __syncthreads();

    if constexpr (!DEFER) {
      stage96<true, true, true, false>(sm, hn, WS, W_R0, 18, r_b0, 1.f, OFF_AP, 0, wave, lane);
      __syncthreads();
      stage96<true, true, true, false>(sm, OFF_AP, WS, W_R1, 18, r_b1, 1.f, OFF_MS, 0, wave, lane);
      __syncthreads();
      if (wave < 6) {
        const int rt6 = wave;
        const short* asb = reinterpret_cast<const short*>(sm + OFF_MS);
        const int row = rt6 * 16 + rl;
        short8v a2[3];
        #pragma unroll
        for (int kt = 0; kt < 3; ++kt)
          a2[kt] = *reinterpret_cast<const short8v*>(asb + row * LDB + kt * 32 + q * 8);
        float4v acc = {0,0,0,0};
        #pragma unroll
        for (int kt = 0; kt < 3; ++kt) {
          const short* bp = WS + W_R2 + kt * 512 + lane * 8;
          acc = mfma2(a2[kt], *reinterpret_cast<const short8v*>(bp),
                      *reinterpret_cast<const short8v*>(bp + 3 * 512), acc);
        }
        if (rl < NOUT) {
          float* op = out + ((size_t)it * BATCH + b) * NN * NOUT;
          #pragma unroll
          for (int j = 0; j < 4; ++j) {
            const int r2 = rt6 * 16 + q * 4 + j;
            if (r2 < NN) op[r2 * NOUT + rl] = acc[j] + r_b2[rl];
          }
        }
      }
      __syncthreads();
    }
  }
}

// ---------------- deferred readout kernel: grid (BATCH, iters), 53.7KB LDS -> 3 blk/CU ----------------
constexpr int RO_H  = 0;
constexpr int RO_B1 = 4212;
constexpr int RO_B2 = 8424;
constexpr int RO_F  = 13416;  // + pad so row-95 fragment reads stay in-bounds

__global__ __launch_bounds__(BLOCK)
void readout_kernel(const short* __restrict__ hist, const short* __restrict__ WS,
                    const float* __restrict__ r_b0, const float* __restrict__ r_b1,
                    const float* __restrict__ r_b2, float* __restrict__ out)
{
  __shared__ float sm[RO_F];
  const int b = blockIdx.x, it = blockIdx.y;
  const int tid = threadIdx.x, wave = tid >> 6, lane = tid & 63;
  const int rl = lane & 15, q = lane >> 4;

  short* hx = reinterpret_cast<short*>(sm + RO_H);
  const short* src = hist + (size_t)(it * BATCH + b) * (NN * HID);
  for (int t = tid; t < NN * HID; t += BLOCK) {
    const int n = t / HID, c = t - n * HID;
    hx[n * LDB + c] = src[t];
  }
  __syncthreads();
  stage96<true, true, true, false>(sm, RO_H,  WS, W_R0, 18, r_b0, 1.f, RO_B1, 0, wave, lane);
  __syncthreads();
  stage96<true, true, true, false>(sm, RO_B1, WS, W_R1, 18, r_b1, 1.f, RO_B2, 0, wave, lane);
  __syncthreads();
  if (wave < 6) {
    const int rt6 = wave;
    const short* asb = reinterpret_cast<const short*>(sm + RO_B2);
    const int row = rt6 * 16 + rl;
    short8v a2[3];
    #pragma unroll
    for (int kt = 0; kt < 3; ++kt)
      a2[kt] = *reinterpret_cast<const short8v*>(asb + row * LDB + kt * 32 + q * 8);
    float4v acc = {0,0,0,0};
    #pragma unroll
    for (int kt = 0; kt < 3; ++kt) {
      const short* bp = WS + W_R2 + kt * 512 + lane * 8;
      acc = mfma2(a2[kt], *reinterpret_cast<const short8v*>(bp),
                  *reinterpret_cast<const short8v*>(bp + 3 * 512), acc);
    }
    if (rl < NOUT) {
      float* op = out + ((size_t)it * BATCH + b) * NN * NOUT;
      #pragma unroll
      for (int j = 0; j < 4; ++j) {
        const int r2 = rt6 * 16 + q * 4 + j;
        if (r2 < NN) op[r2 * NOUT + rl] = acc[j] + r_b2[rl];
      }
    }
  }
}

extern "C" void kernel_launch(void* const* d_in, const int* in_sizes, int n_in,
                              void* d_out, int out_size, void* d_ws, size_t ws_size,
                              hipStream_t stream) {
  (void)in_sizes; (void)n_in;
  const int* grids = (const int*)d_in[0];
  const int* iters = (const int*)d_in[1];
  const float *emb = (const float*)d_in[2],
    *in_w0 = (const float*)d_in[3],  *in_b0 = (const float*)d_in[4],
    *in_w1 = (const float*)d_in[5],  *in_b1 = (const float*)d_in[6],
    *in_w2 = (const float*)d_in[7],  *in_b2 = (const float*)d_in[8],
    *rel_w0 = (const float*)d_in[9],  *rel_b0 = (const float*)d_in[10],
    *rel_w1 = (const float*)d_in[11], *rel_b1 = (const float*)d_in[12],
    *rel_w2 = (const float*)d_in[13], *rel_b2 = (const float*)d_in[14],
    *g_w0 = (const float*)d_in[15], *g_b0 = (const float*)d_in[16],
    *g_w1 = (const float*)d_in[17], *g_b1 = (const float*)d_in[18],
    *g_w2 = (const float*)d_in[19], *g_b2 = (const float*)d_in[20],
    *wih = (const float*)d_in[21], *whh = (const float*)d_in[22],
    *bih = (const float*)d_in[23], *bhh = (const float*)d_in[24],
    *r_w0 = (const float*)d_in[25], *r_b0 = (const float*)d_in[26],
    *r_w1 = (const float*)d_in[27], *r_b1 = (const float*)d_in[28],
    *r_w2 = (const float*)d_in[29], *r_b2 = (const float*)d_in[30],
    *c0 = (const float*)d_in[31];
  short* ws = (short*)d_ws;
  short* hist = ws + HISTOFF;
  const int iters_h = out_size / (BATCH * NN * NOUT);
  const size_t need = ((size_t)HISTOFF + (size_t)iters_h * BATCH * NN * HID) * sizeof(short);
  const bool defer = ws_size >= need && iters_h > 0;

  pack_kernel<<<dim3(328), dim3(64), 0, stream>>>(
      rel_w0, rel_w1, rel_w2, g_w0, g_w1, g_w2, wih, whh,
      r_w0, r_w1, r_w2, in_w1, in_w2, rel_b2, g_b2, ws);
  if (defer) {
    rrn_kernel<true><<<dim3(BATCH), dim3(BLOCK), 0, stream>>>(
        grids, iters, emb, in_w0, in_b0, in_b1, in_b2,
        rel_b0, rel_b1, g_b0, g_b1,
        bih, bhh, r_b0, r_b1, r_b2, c0, (const short*)ws, hist, (float*)d_out);
    readout_kernel<<<dim3(BATCH, iters_h), dim3(BLOCK), 0, stream>>>(
        hist, (const short*)ws, r_b0, r_b1, r_b2, (float*)d_out);
  } else {
    rrn_kernel<false><<<dim3(BATCH), dim3(BLOCK), 0, stream>>>(
        grids, iters, emb, in_w0, in_b0, in_b1, in_b2,
        rel_b0, rel_b1, g_b0, g_b1,
        bih, bhh, r_b0, r_b1, r_b2, c0, (const short*)ws, hist, (float*)d_out);
  }
}